// Round 5
// baseline (559.223 us; speedup 1.0000x reference)
//
#include <hip/hip_runtime.h>
#include <stdint.h>

#define B_SZ 32
#define T_SZ 300
#define F_IN 3072
#define F_HID 410
#define F_OUT 10
#define M_SZ (B_SZ * T_SZ)              // 9600
#define N_PAD 448                       // a1 row stride = gemm1 N (7 x 64)
#define A2_STRIDE 16
#define NCHUNK 10
#define CLEN 30
#define NKB (F_IN / 256)                // 12 K-blocks of 256
#define MT_CNT (M_SZ / 64)              // 150 m-tiles
#define W1_UNITS 672                    // 448*3072/8/256
#define RNG_UNITS 14400                 // 921600*4/256

// Ticket space for the fused rnggemm kernel:
//   [0,672)            : W1 fp32->fp8 swizzle units
//   [672,864)          : RNG units of mtile 0,1 (96 each)
//   [864,864+148*103)  : group g: {96 RNG units of mtile g+2, 7 GEMM tiles of mtile g}
//   [16108,16122)      : GEMM tiles of mtile 148,149
// GEMM tile (mt,nt) is gated on rngcnt[mt]==96 && w1cnt==672; every producer
// ticket precedes its consumer, gates only reference non-blocking unit types,
// and grid <= resident capacity => deadlock-free with static stride pickup.
#define TK_RNG0 672
#define TK_GRP 864
#define TK_TAIL (TK_GRP + 148 * 103)    // 16108
#define NTICK (TK_TAIL + 14)            // 16122

// f32(exp(f32(-0.1))) — PSP decay, matches XLA's correctly-rounded exp
#define DECAY 0.90483741803595957f
#define THETA 10.0f
#define KS2 (0x1BD11BDAu ^ 42u)

typedef __attribute__((ext_vector_type(8))) int i32x8;
typedef __attribute__((ext_vector_type(16))) float f32x16;

// FORCED single-instruction rotate-left, in-place. v_alignbit_b32 x,x,x,(32-r)
// = rotl(r). (R3: prep is at the sustainable VALU issue floor.)
#define TF_R(r) { x0 += x1; \
  asm("v_alignbit_b32 %0, %0, %0, %1" : "+v"(x1) : "n"(32 - (r))); \
  x1 ^= x0; }

// JAX partitionable threefry2x32, key=(0,42), ctr=(0, x1i-42). x0 key-add is 0
// (elided); x1 key-add folded into caller's x1i = base + 42 + jj. Returns o0^o1.
__device__ __forceinline__ uint32_t tf_bits(uint32_t x1i) {
  uint32_t x0 = 0u, x1 = x1i;
  TF_R(13) TF_R(15) TF_R(26) TF_R(6)
  x0 += 42u; x1 += KS2 + 1u;
  TF_R(17) TF_R(29) TF_R(16) TF_R(24)
  x0 += KS2; x1 += 2u;
  TF_R(13) TF_R(15) TF_R(26) TF_R(6)
  x1 += 42u + 3u;
  TF_R(17) TF_R(29) TF_R(16) TF_R(24)
  x0 += 42u; x1 += KS2 + 4u;
  TF_R(13) TF_R(15) TF_R(26) TF_R(6)
  x0 += KS2; x1 += 5u;
  return x0 ^ x1;
}

// async global->LDS, 16 B per lane; LDS dest = wave-uniform base + lane*16
__device__ __forceinline__ void gld16(const void* g, void* l) {
  __builtin_amdgcn_global_load_lds(
      (const __attribute__((address_space(1))) uint32_t*)g,
      (__attribute__((address_space(3))) uint32_t*)l, 16, 0, 0);
}

// Counters live in a2's unused padding (col 10 of rows 0..151):
// slot 0 = unused, slot 1 = w1cnt, slot 2+mt = rngcnt[mt].
__device__ __forceinline__ uint32_t* ctr_slot(uint32_t* ctr, int i) {
  return ctr + (size_t)i * A2_STRIDE + 10;
}

__global__ __launch_bounds__(256) void zeroctr(uint32_t* __restrict__ ctr) {
  if (threadIdx.x < 152) *ctr_slot(ctr, threadIdx.x) = 0u;
}

// --- unit bodies (verbatim R4 prep/gemm1 math) ------------------------------

__device__ __forceinline__ void w1_unit(int u, int tid,
                                        const float* __restrict__ W1,
                                        uint8_t* __restrict__ W1s) {
  int idx = u * 256 + tid;
  int g = idx * 8;
  int n = g / F_IN;
  int k = g - n * F_IN;
  uint32_t d0 = 0u, d1 = 0u;
  if (n < F_HID) {
    const float* s = W1 + (size_t)n * F_IN + k;
    float4 v0 = ((const float4*)s)[0];
    float4 v1 = ((const float4*)s)[1];
    int t0 = __builtin_amdgcn_cvt_pk_fp8_f32(v0.x, v0.y, 0, false);
    t0 = __builtin_amdgcn_cvt_pk_fp8_f32(v0.z, v0.w, t0, true);
    int t1 = __builtin_amdgcn_cvt_pk_fp8_f32(v1.x, v1.y, 0, false);
    t1 = __builtin_amdgcn_cvt_pk_fp8_f32(v1.z, v1.w, t1, true);
    d0 = (uint32_t)t0; d1 = (uint32_t)t1;
  }
  int nt = n >> 6, r = n & 63;
  int kb = k >> 8, c = (k >> 4) & 15, half = (k >> 3) & 1;
  size_t dst = ((((size_t)nt * NKB + kb) * 64 + r) * 16 + (c ^ (r & 15))) * 16 + half * 8;
  *(uint2*)(W1s + dst) = make_uint2(d0, d1);
}

__device__ __forceinline__ void rng_unit(int bp, int tid,
                                         const float* __restrict__ inp,
                                         uint32_t* __restrict__ sbitsT) {
  uint32_t idx = (uint32_t)bp * 256u + tid;  // [0, 3686400)
  uint32_t q = idx & 3u;          // byte within word
  uint32_t j = idx >> 2;          // word index [0, 921600)
  uint32_t r = j & 63u;
  uint32_t t1 = j >> 6;
  uint32_t wi = t1 & 7u;
  uint32_t t2 = t1 >> 3;          // (mt*12 + kb) in [0, 1800)
  uint32_t kb = t2 % (uint32_t)NKB;
  uint32_t mt = t2 / (uint32_t)NKB;
  uint32_t m = mt * 64u + r;      // GEMM row = b*300 + t
  uint32_t b = m / (uint32_t)T_SZ;
  uint32_t f = (kb * 8u + wi) * 32u + q * 8u;
  const float* p = inp + b * F_IN + f;
  float4 va = ((const float4*)p)[0];
  float4 vb = ((const float4*)p)[1];
  uint32_t T0 = (uint32_t)ceilf(va.x * 8388608.0f);
  uint32_t T1 = (uint32_t)ceilf(va.y * 8388608.0f);
  uint32_t T2 = (uint32_t)ceilf(va.z * 8388608.0f);
  uint32_t T3 = (uint32_t)ceilf(va.w * 8388608.0f);
  uint32_t T4 = (uint32_t)ceilf(vb.x * 8388608.0f);
  uint32_t T5 = (uint32_t)ceilf(vb.y * 8388608.0f);
  uint32_t T6 = (uint32_t)ceilf(vb.z * 8388608.0f);
  uint32_t T7 = (uint32_t)ceilf(vb.w * 8388608.0f);
  uint32_t b42 = m * (uint32_t)F_IN + f + 42u;   // counter base + key lo
  uint32_t w = 0u;
#define GEN(jj, Tn) { uint32_t bits = tf_bits(b42 + (jj)); \
  w |= ((bits >> 9) < (Tn)) ? (1u << (jj)) : 0u; }
  GEN(0, T0) GEN(1, T1) GEN(2, T2) GEN(3, T3)
  GEN(4, T4) GEN(5, T5) GEN(6, T6) GEN(7, T7)
#undef GEN
  ((uint8_t*)sbitsT)[idx] = (uint8_t)w;   // byte q of word j: bits [8q, 8q+8)
}

// R4's double-buffered MX-fp8 MFMA 64x64 tile, as a callable unit.
__device__ __forceinline__ void gemm_unit(int mtile, int nt, int tid,
                                          const uint32_t* __restrict__ sbitsT,
                                          const uint8_t* __restrict__ W1s,
                                          float* __restrict__ a1,
                                          uint32_t* sAT, uint8_t* sB) {
  const int m0 = mtile * 64;
  const int n0 = nt * 64;
  const int wv = tid >> 6, lane = tid & 63;
  const int wm = (wv & 1) * 32, wn = (wv >> 1) * 32;
  const int l31 = lane & 31, lh = lane >> 5;

  const uint8_t* gB0 = W1s + (size_t)nt * NKB * 16384;
  const uint8_t* gA0 = (const uint8_t*)sbitsT + (size_t)mtile * NKB * 2048;

  auto STAGE = [&](int buf, int kb) {
    const uint8_t* gB = gB0 + (size_t)kb * 16384;
#pragma unroll
    for (int q = 0; q < 4; ++q)
      gld16(gB + (wv * 4 + q) * 1024 + lane * 16,
            sB + buf * 16384 + (wv * 4 + q) * 1024);
    if (wv < 2)
      gld16(gA0 + (size_t)kb * 2048 + wv * 1024 + lane * 16,
            (uint8_t*)sAT + buf * 2048 + wv * 1024);
  };

  f32x16 acc;
#pragma unroll
  for (int e = 0; e < 16; ++e) acc[e] = 0.0f;

  STAGE(0, 0);
  __syncthreads();             // prologue: only exposed DMA wait
  int cur = 0;
  for (int kb = 0; kb < NKB; ++kb) {
    if (kb + 1 < NKB) STAGE(cur ^ 1, kb + 1);   // in flight during compute
    const uint8_t* sBc = sB + cur * 16384;
    const uint32_t* sATc = sAT + cur * 512;
#pragma unroll
    for (int sub = 0; sub < 4; ++sub) {
      int row = wn + l31;
      int cb = sub * 4 + lh * 2;
      uint4 u0 = *(uint4*)&sBc[row * 256 + (((cb + 0) ^ (row & 15)) << 4)];
      uint4 u1 = *(uint4*)&sBc[row * 256 + (((cb + 1) ^ (row & 15)) << 4)];
      i32x8 bfr;
      bfr[0] = u0.x; bfr[1] = u0.y; bfr[2] = u0.z; bfr[3] = u0.w;
      bfr[4] = u1.x; bfr[5] = u1.y; bfr[6] = u1.z; bfr[7] = u1.w;
      uint32_t w = sATc[(sub * 2 + lh) * 64 + wm + l31];
      i32x8 afr;
#pragma unroll
      for (int j = 0; j < 8; ++j) {
        uint32_t n = (w >> (4 * j)) & 15u;
        afr[j] = (int)(((n * 0x204081u) & 0x01010101u) * 0x38u);
      }
      acc = __builtin_amdgcn_mfma_scale_f32_32x32x64_f8f6f4(
          afr, bfr, acc, 0, 0, 0, 127, 0, 127);
    }
    __syncthreads();   // drains this wave's DMA (next buf ready) + LDS reuse
    cur ^= 1;
  }
  int col = n0 + wn + l31;
#pragma unroll
  for (int rg = 0; rg < 16; ++rg) {
    int row = m0 + wm + (rg & 3) + 8 * (rg >> 2) + 4 * lh;
    a1[(size_t)row * N_PAD + col] = acc[rg];
  }
}

// Fused prep+gemm1. RNG (pure VALU) and GEMM (MFMA+DMA) units co-scheduled on
// the same CUs — separate issue pipes overlap (m114). Static-stride tickets,
// relaxed-load gates, release via syncthreads+threadfence+atomicAdd (the
// cross-XCD pattern R1 validated with absmax 0.0).
__global__ __launch_bounds__(256, 4) void rnggemm(
    const float* __restrict__ inp, const float* __restrict__ W1,
    uint8_t* __restrict__ W1s, uint32_t* __restrict__ sbitsT,
    float* __restrict__ a1, uint32_t* __restrict__ ctr) {
  __shared__ uint32_t sAT[2 * 512];    // 4 KB
  __shared__ uint8_t sB[2 * 16384];    // 32 KB
  const int tid = threadIdx.x;
  const int G = gridDim.x;
  for (int T = blockIdx.x; T < NTICK; T += G) {
    if (T < W1_UNITS) {
      w1_unit(T, tid, W1, W1s);
      __syncthreads();   // vmcnt(0) drain of all threads' stores
      if (tid == 0) { __threadfence(); atomicAdd(ctr_slot(ctr, 1), 1u); }
    } else {
      int x = T - TK_RNG0;
      int bp = -1, mtile = 0, nt = 0;
      if (x < 192) {
        bp = x;                                  // RNG of mtile 0,1
      } else {
        x -= 192;
        if (T < TK_TAIL) {
          int g = x / 103, r = x - g * 103;
          if (r < 96) bp = (g + 2) * 96 + r;     // RNG of mtile g+2
          else { mtile = g; nt = r - 96; }       // GEMM of mtile g
        } else {
          int y = T - TK_TAIL;
          mtile = 148 + y / 7; nt = y - (y / 7) * 7;
        }
      }
      if (bp >= 0) {
        rng_unit(bp, tid, inp, sbitsT);
        __syncthreads();   // vmcnt(0) drain of all threads' stores
        if (tid == 0) { __threadfence(); atomicAdd(ctr_slot(ctr, 2 + bp / 96), 1u); }
      } else {
        if (tid == 0) {
          while (__hip_atomic_load(ctr_slot(ctr, 1), __ATOMIC_RELAXED,
                                   __HIP_MEMORY_SCOPE_AGENT) < (uint32_t)W1_UNITS ||
                 __hip_atomic_load(ctr_slot(ctr, 2 + mtile), __ATOMIC_RELAXED,
                                   __HIP_MEMORY_SCOPE_AGENT) < 96u)
            __builtin_amdgcn_s_sleep(2);
          __threadfence();   // acquire: invalidate L1 before gld16 reads
        }
        __syncthreads();
        gemm_unit(mtile, nt, tid, sbitsT, W1s, a1, sAT, sB);
      }
    }
  }
}

// PSP phase A: per-(b,chunk,o) partial scan from 0; partials overwrite a1;
// raw chunk finals -> fin[b][c][o].
__global__ __launch_bounds__(256) void psp1_partial(float* __restrict__ a1,
                                                    float* __restrict__ fin) {
  int idx = blockIdx.x * 256 + threadIdx.x;   // 32*10*448 = 143360
  if (idx >= B_SZ * NCHUNK * N_PAD) return;
  int o = idx % N_PAD;
  int bc = idx / N_PAD;
  int c = bc % NCHUNK;
  int b = bc / NCHUNK;
  float* p = a1 + ((size_t)(b * T_SZ + c * CLEN)) * N_PAD + o;
  float u = 0.0f;
#pragma unroll
  for (int i = 0; i < CLEN; ++i) {
    u = __fadd_rn(__fmul_rn(DECAY, u), p[(size_t)i * N_PAD]);
    p[(size_t)i * N_PAD] = u;
  }
  fin[(size_t)bc * N_PAD + o] = u;
}

// Chunk-prefix scan, in-place over fin (R4). Same expression chain as the
// original inline combine => bit-identical.
__global__ __launch_bounds__(256) void fscan(float* __restrict__ fin) {
  int idx = blockIdx.x * 256 + threadIdx.x;   // 32*448 = 14336
  if (idx >= B_SZ * N_PAD) return;
  int o = idx % N_PAD;
  int b = idx / N_PAD;
  float* f = fin + (size_t)b * NCHUNK * N_PAD + o;
  float d30 = 1.0f;
#pragma unroll
  for (int i = 0; i < CLEN; ++i) d30 *= DECAY;
  float v[NCHUNK - 1];
#pragma unroll
  for (int c = 0; c < NCHUNK - 1; ++c) v[c] = f[(size_t)c * N_PAD];
  float F = 0.0f;
  f[0] = 0.0f;
#pragma unroll
  for (int c = 1; c < NCHUNK; ++c) {
    F = v[c - 1] + d30 * F;
    f[(size_t)c * N_PAD] = F;
  }
}

// Fused PSP apply + layer-2 GEMM. One wave per (b,t). fin holds pre-scanned F~.
__global__ __launch_bounds__(256) void apply_gemm2(const float* __restrict__ a1,
                                                   const float* __restrict__ fin,
                                                   const float* __restrict__ W2,
                                                   float* __restrict__ a2) {
  __shared__ float sW2[F_OUT * F_HID];   // 16.4 KB
  for (int i = threadIdx.x; i < F_OUT * F_HID; i += 256) sW2[i] = W2[i];
  __syncthreads();
  int m = blockIdx.x * 4 + (threadIdx.x >> 6);
  int lane = threadIdx.x & 63;
  int b = m / T_SZ, t = m % T_SZ;
  int c = t / CLEN, tl = t % CLEN;
  float dp = DECAY;
  for (int i = 0; i < tl; ++i) dp *= DECAY;   // decay^(tl+1), wave-uniform
  const float* frow = fin + (size_t)(b * NCHUNK + c) * N_PAD;
  float p[F_OUT];
#pragma unroll
  for (int o = 0; o < F_OUT; ++o) p[o] = 0.0f;
#pragma unroll
  for (int j = 0; j < 7; ++j) {
    int hh = lane + j * 64;
    float u = a1[(size_t)m * N_PAD + hh];
    if (c > 0) {
      float F = frow[hh];                     // pre-scanned chunk seed
      u = __fadd_rn(u, __fmul_rn(dp, F));
    }
    bool valid = hh < F_HID;
    float s = (u >= THETA && valid) ? 1.0f : 0.0f;
    int hcl = valid ? hh : 0;
#pragma unroll
    for (int o = 0; o < F_OUT; ++o) p[o] = fmaf(s, sW2[o * F_HID + hcl], p[o]);
  }
#pragma unroll
  for (int o = 0; o < F_OUT; ++o)
#pragma unroll
    for (int s = 1; s < 64; s <<= 1) p[o] += __shfl_xor(p[o], s, 64);
  if (lane < F_OUT) a2[(size_t)m * A2_STRIDE + lane] = p[lane];
}

// Layer-2 PSP, chunked, one block per batch; lanes (o,c) in [10x10].
__global__ __launch_bounds__(128) void psp2(const float* __restrict__ a2,
                                            float* __restrict__ out) {
  __shared__ float chf[NCHUNK][F_OUT];
  __shared__ float seed[NCHUNK][F_OUT];
  int b = blockIdx.x;
  int tid = threadIdx.x;
  int o = tid / NCHUNK, c = tid % NCHUNK;
  const float* p = a2 + ((size_t)(b * T_SZ + c * CLEN)) * A2_STRIDE + o;
  float v[CLEN];
  float pa[CLEN];
  if (tid < F_OUT * NCHUNK) {
#pragma unroll
    for (int i = 0; i < CLEN; ++i) v[i] = p[(size_t)i * A2_STRIDE];
    float u = 0.0f;
#pragma unroll
    for (int i = 0; i < CLEN; ++i) {
      u = __fadd_rn(__fmul_rn(DECAY, u), v[i]);
      pa[i] = u;
    }
    chf[c][o] = u;
  }
  __syncthreads();
  if (tid < F_OUT) {
    float d30 = 1.0f;
#pragma unroll
    for (int i = 0; i < CLEN; ++i) d30 *= DECAY;
    float F = 0.0f;
    for (int cc = 0; cc < NCHUNK; ++cc) {
      F = chf[cc][tid] + d30 * F;
      seed[cc][tid] = F;
    }
  }
  __syncthreads();
  if (tid < F_OUT * NCHUNK) {
    float F = (c == 0) ? 0.0f : seed[c - 1][o];
    float dp = DECAY;
    float* q = out + (size_t)b * F_OUT * T_SZ + (size_t)o * T_SZ + c * CLEN;
#pragma unroll
    for (int i = 0; i < CLEN; ++i) {
      float u = (c == 0) ? pa[i] : __fadd_rn(pa[i], __fmul_rn(dp, F));
      q[i] = (u >= THETA) ? 1.0f : 0.0f;
      dp *= DECAY;
    }
  }
}

extern "C" void kernel_launch(void* const* d_in, const int* in_sizes, int n_in,
                              void* d_out, int out_size, void* d_ws, size_t ws_size,
                              hipStream_t stream) {
  const float* inp = (const float*)d_in[0];  // [32,3,32,32]
  const float* W1  = (const float*)d_in[1];  // [410,3072]
  const float* W2  = (const float*)d_in[2];  // [10,410]
  float* out = (float*)d_out;                // [32,10,300]
  char* ws = (char*)d_ws;
  // ws: W1s 1376256 | sbitsT 3686400 | a1 17203200 | fin 573440 | a2 614400
  uint8_t* W1s = (uint8_t*)(ws);
  uint32_t* sbitsT = (uint32_t*)(ws + 1376256);
  float* a1 = (float*)(ws + 1376256 + 3686400);
  float* fin = a1 + (size_t)M_SZ * N_PAD;
  float* a2 = fin + (size_t)B_SZ * NCHUNK * N_PAD;
  uint32_t* ctr = (uint32_t*)a2;  // counters in a2 padding col 10, rows 0..151

  // Grid = resident capacity (blocks/CU from occupancy query, LDS 36.9 KB =>
  // expect 4) so every block runs from t0 — required by the deadlock proof.
  static int NBLK = 0;
  if (NBLK == 0) {
    int t = 0;
    if (hipOccupancyMaxActiveBlocksPerMultiprocessor(&t, rnggemm, 256, 0) != hipSuccess || t < 1)
      t = 1;
    if (t > 4) t = 4;
    NBLK = t * 256;
  }

  zeroctr<<<dim3(1), dim3(256), 0, stream>>>(ctr);
  rnggemm<<<dim3(NBLK), dim3(256), 0, stream>>>(inp, W1, W1s, sbitsT, a1, ctr);
  psp1_partial<<<dim3((B_SZ * NCHUNK * N_PAD) / 256), dim3(256), 0, stream>>>(a1, fin);
  fscan<<<dim3((B_SZ * N_PAD) / 256), dim3(256), 0, stream>>>(fin);
  apply_gemm2<<<dim3(M_SZ / 4), dim3(256), 0, stream>>>(a1, fin, W2, a2);
  psp2<<<dim3(B_SZ), dim3(128), 0, stream>>>(a2, out);
}

// Round 6
// 331.135 us; speedup vs baseline: 1.6888x; 1.6888x over previous
//
#include <hip/hip_runtime.h>
#include <stdint.h>

#define B_SZ 32
#define T_SZ 300
#define F_IN 3072
#define F_HID 410
#define F_OUT 10
#define M_SZ (B_SZ * T_SZ)              // 9600
#define N_PAD 448                       // a1 row stride = gemm1 N (7 x 64)
#define A2_STRIDE 16
#define NCHUNK 10
#define CLEN 30
#define NKB (F_IN / 256)                // 12 K-blocks of 256
#define MT_CNT (M_SZ / 64)              // 150 m-tiles
#define NTILES (MT_CNT * (N_PAD / 64))  // 1050 gemm tiles
#define W1_BLOCKS 672                   // 448*3072/8/256
#define RNG_BLOCKS 14400                // 921600*4/256
#define AG2_UNITS (M_SZ / 4)            // 2400

// f32(exp(f32(-0.1))) — PSP decay, matches XLA's correctly-rounded exp
#define DECAY 0.90483741803595957f
#define THETA 10.0f
#define KS2 (0x1BD11BDAu ^ 42u)

typedef __attribute__((ext_vector_type(8))) int i32x8;
typedef __attribute__((ext_vector_type(16))) float f32x16;

// FORCED single-instruction rotate-left, in-place. v_alignbit_b32 x,x,x,(32-r)
// = rotl(r). (R3: prep is at the sustainable VALU issue floor.)
#define TF_R(r) { x0 += x1; \
  asm("v_alignbit_b32 %0, %0, %0, %1" : "+v"(x1) : "n"(32 - (r))); \
  x1 ^= x0; }

// JAX partitionable threefry2x32, key=(0,42), ctr=(0, x1i-42). x0 key-add is 0
// (elided); x1 key-add folded into caller's x1i = base + 42 + jj. Returns o0^o1.
__device__ __forceinline__ uint32_t tf_bits(uint32_t x1i) {
  uint32_t x0 = 0u, x1 = x1i;
  TF_R(13) TF_R(15) TF_R(26) TF_R(6)
  x0 += 42u; x1 += KS2 + 1u;
  TF_R(17) TF_R(29) TF_R(16) TF_R(24)
  x0 += KS2; x1 += 2u;
  TF_R(13) TF_R(15) TF_R(26) TF_R(6)
  x1 += 42u + 3u;
  TF_R(17) TF_R(29) TF_R(16) TF_R(24)
  x0 += 42u; x1 += KS2 + 4u;
  TF_R(13) TF_R(15) TF_R(26) TF_R(6)
  x0 += KS2; x1 += 5u;
  return x0 ^ x1;
}

// async global->LDS, 16 B per lane; LDS dest = wave-uniform base + lane*16
__device__ __forceinline__ void gld16(const void* g, void* l) {
  __builtin_amdgcn_global_load_lds(
      (const __attribute__((address_space(1))) uint32_t*)g,
      (__attribute__((address_space(3))) uint32_t*)l, 16, 0, 0);
}

// Barrier counters live in a2's unused padding (cols 10..11 of rows 0,4,8,12;
// ag2 writes cols <10, psp2 reads cols <10). 8B-aligned u64 slots.
__device__ __forceinline__ unsigned long long* bslot(float* a2, int i) {
  return (unsigned long long*)((char*)a2 + 40 + (size_t)i * 64);
}

// Merged prep (unchanged math). Block 0 additionally zeroes the 4 tail
// barrier counters (runs before tail in stream order every replay).
__global__ __launch_bounds__(256) void prep(const float* __restrict__ inp,
                                            const float* __restrict__ W1,
                                            uint8_t* __restrict__ W1s,
                                            uint32_t* __restrict__ sbitsT,
                                            float* __restrict__ a2) {
  if (blockIdx.x == 0 && threadIdx.x < 4) *bslot(a2, threadIdx.x) = 0ull;
  if (blockIdx.x < W1_BLOCKS) {
    int idx = blockIdx.x * 256 + threadIdx.x;
    int g = idx * 8;
    int n = g / F_IN;
    int k = g - n * F_IN;
    uint32_t d0 = 0u, d1 = 0u;
    if (n < F_HID) {
      const float* s = W1 + (size_t)n * F_IN + k;
      float4 v0 = ((const float4*)s)[0];
      float4 v1 = ((const float4*)s)[1];
      int t0 = __builtin_amdgcn_cvt_pk_fp8_f32(v0.x, v0.y, 0, false);
      t0 = __builtin_amdgcn_cvt_pk_fp8_f32(v0.z, v0.w, t0, true);
      int t1 = __builtin_amdgcn_cvt_pk_fp8_f32(v1.x, v1.y, 0, false);
      t1 = __builtin_amdgcn_cvt_pk_fp8_f32(v1.z, v1.w, t1, true);
      d0 = (uint32_t)t0; d1 = (uint32_t)t1;
    }
    int nt = n >> 6, r = n & 63;
    int kb = k >> 8, c = (k >> 4) & 15, half = (k >> 3) & 1;
    size_t dst = ((((size_t)nt * NKB + kb) * 64 + r) * 16 + (c ^ (r & 15))) * 16 + half * 8;
    *(uint2*)(W1s + dst) = make_uint2(d0, d1);
  } else {
    uint32_t idx = (blockIdx.x - W1_BLOCKS) * 256u + threadIdx.x;  // [0, 3686400)
    uint32_t q = idx & 3u;          // byte within word
    uint32_t j = idx >> 2;          // word index [0, 921600)
    uint32_t r = j & 63u;
    uint32_t t1 = j >> 6;
    uint32_t wi = t1 & 7u;
    uint32_t t2 = t1 >> 3;          // (mt*12 + kb) in [0, 1800)
    uint32_t kb = t2 % (uint32_t)NKB;
    uint32_t mt = t2 / (uint32_t)NKB;
    uint32_t m = mt * 64u + r;      // GEMM row = b*300 + t
    uint32_t b = m / (uint32_t)T_SZ;
    uint32_t f = (kb * 8u + wi) * 32u + q * 8u;
    const float* p = inp + b * F_IN + f;
    float4 va = ((const float4*)p)[0];
    float4 vb = ((const float4*)p)[1];
    uint32_t T0 = (uint32_t)ceilf(va.x * 8388608.0f);
    uint32_t T1 = (uint32_t)ceilf(va.y * 8388608.0f);
    uint32_t T2 = (uint32_t)ceilf(va.z * 8388608.0f);
    uint32_t T3 = (uint32_t)ceilf(va.w * 8388608.0f);
    uint32_t T4 = (uint32_t)ceilf(vb.x * 8388608.0f);
    uint32_t T5 = (uint32_t)ceilf(vb.y * 8388608.0f);
    uint32_t T6 = (uint32_t)ceilf(vb.z * 8388608.0f);
    uint32_t T7 = (uint32_t)ceilf(vb.w * 8388608.0f);
    uint32_t b42 = m * (uint32_t)F_IN + f + 42u;   // counter base + key lo
    uint32_t w = 0u;
#define GEN(jj, Tn) { uint32_t bits = tf_bits(b42 + (jj)); \
  w |= ((bits >> 9) < (Tn)) ? (1u << (jj)) : 0u; }
    GEN(0, T0) GEN(1, T1) GEN(2, T2) GEN(3, T3)
    GEN(4, T4) GEN(5, T5) GEN(6, T6) GEN(7, T7)
#undef GEN
    ((uint8_t*)sbitsT)[idx] = (uint8_t)w;   // byte q of word j: bits [8q, 8q+8)
  }
}

// Ticket-based grid barrier: arrival = fence + atomicAdd; wait = relaxed
// agent-scope LOAD (R2 fix: never spin on an RMW). u64 counters, monotonic
// across replays; prep zeroes them each launch.
__device__ __forceinline__ void gbar(unsigned long long* c) {
  __syncthreads();
  if (threadIdx.x == 0) {
    __threadfence();                                  // release
    unsigned long long t = atomicAdd(c, 1ull);
    unsigned long long g = (unsigned long long)gridDim.x;
    unsigned long long tgt = t - (t % g) + g;
    while (__hip_atomic_load(c, __ATOMIC_RELAXED, __HIP_MEMORY_SCOPE_AGENT) < tgt)
      __builtin_amdgcn_s_sleep(8);
  }
  __syncthreads();
  __threadfence();                                    // acquire
}

// Fused tail: gemm1 -> psp1 -> fscan -> apply_gemm2 -> psp2, one dispatch,
// 4 grid barriers. R1/R2's fused-tail failure is now attributed to the old
// ag2 dependent fin-chain at 2 blocks/CU (removed by fscan in R4) — with no
// dependent chains left and grid = query-verified full residency (single-
// buffered gemm => LDS 18.4KB => ~8 blocks/CU), every phase runs at >= ~its
// natural occupancy. Eliminates 4 inter-dispatch gaps (~10us each).
__global__ __launch_bounds__(256) void tail(
    const uint32_t* __restrict__ sbitsT, const uint8_t* __restrict__ W1s,
    float* __restrict__ a1, float* __restrict__ fin,
    const float* __restrict__ W2, float* __restrict__ a2,
    float* __restrict__ out) {
  __shared__ __align__(16) char smem[18432];  // gemm: 2KB sAT + 16KB sB; ag2: sW2 16.4KB; psp2: chf/seed
  const int tid = threadIdx.x;
  const int G = gridDim.x;

  // ---------------- phase 1: gemm1 (single-buffered R3 body) ---------------
  {
    uint32_t* sAT = (uint32_t*)smem;            // [8][64]
    uint8_t* sB = (uint8_t*)(smem + 2048);      // [64][256] swizzled
    const int wv = tid >> 6, lane = tid & 63;
    const int wm = (wv & 1) * 32, wn = (wv >> 1) * 32;
    const int l31 = lane & 31, lh = lane >> 5;
    for (int vb = blockIdx.x; vb < NTILES; vb += G) {
      const int mtile = vb % MT_CNT;
      const int nt = vb / MT_CNT;
      const int m0 = mtile * 64;
      const int n0 = nt * 64;
      const uint8_t* gB0 = W1s + (size_t)nt * NKB * 16384;
      const uint8_t* gA0 = (const uint8_t*)sbitsT + (size_t)mtile * NKB * 2048;

      f32x16 acc;
#pragma unroll
      for (int e = 0; e < 16; ++e) acc[e] = 0.0f;

      for (int kb = 0; kb < NKB; ++kb) {
        const uint8_t* gB = gB0 + (size_t)kb * 16384;
#pragma unroll
        for (int q = 0; q < 4; ++q)
          gld16(gB + (wv * 4 + q) * 1024 + lane * 16, &sB[(wv * 4 + q) * 1024]);
        if (wv < 2)
          gld16(gA0 + (size_t)kb * 2048 + wv * 1024 + lane * 16,
                (uint8_t*)sAT + wv * 1024);
        __syncthreads();   // vmcnt drain + visibility
#pragma unroll
        for (int sub = 0; sub < 4; ++sub) {
          int row = wn + l31;
          int cb = sub * 4 + lh * 2;
          uint4 u0 = *(uint4*)&sB[row * 256 + (((cb + 0) ^ (row & 15)) << 4)];
          uint4 u1 = *(uint4*)&sB[row * 256 + (((cb + 1) ^ (row & 15)) << 4)];
          i32x8 bfr;
          bfr[0] = u0.x; bfr[1] = u0.y; bfr[2] = u0.z; bfr[3] = u0.w;
          bfr[4] = u1.x; bfr[5] = u1.y; bfr[6] = u1.z; bfr[7] = u1.w;
          uint32_t w = sAT[(sub * 2 + lh) * 64 + wm + l31];
          i32x8 afr;
#pragma unroll
          for (int j = 0; j < 8; ++j) {
            uint32_t n = (w >> (4 * j)) & 15u;
            afr[j] = (int)(((n * 0x204081u) & 0x01010101u) * 0x38u);
          }
          acc = __builtin_amdgcn_mfma_scale_f32_32x32x64_f8f6f4(
              afr, bfr, acc, 0, 0, 0, 127, 0, 127);
        }
        __syncthreads();   // LDS free before next kb's DMA
      }
      int col = n0 + wn + l31;
#pragma unroll
      for (int rg = 0; rg < 16; ++rg) {
        int row = m0 + wm + (rg & 3) + 8 * (rg >> 2) + 4 * lh;
        a1[(size_t)row * N_PAD + col] = acc[rg];
      }
    }
  }
  gbar(bslot(a2, 0));

  // Stage sW2 now (LDS free after gemm); visibility to the block is given by
  // the next gbar's __syncthreads, before any use in phase 4.
  float* sW2 = (float*)smem;   // 16.4 KB
  for (int i = tid; i < F_OUT * F_HID; i += 256) sW2[i] = W2[i];

  // ---------------- phase 2: psp1_partial ----------------------------------
  for (int idx = blockIdx.x * 256 + tid; idx < B_SZ * NCHUNK * N_PAD;
       idx += G * 256) {
    int o = idx % N_PAD;
    int bc = idx / N_PAD;
    int c = bc % NCHUNK;
    int b = bc / NCHUNK;
    float* p = a1 + ((size_t)(b * T_SZ + c * CLEN)) * N_PAD + o;
    float u = 0.0f;
#pragma unroll
    for (int i = 0; i < CLEN; ++i) {
      u = __fadd_rn(__fmul_rn(DECAY, u), p[(size_t)i * N_PAD]);
      p[(size_t)i * N_PAD] = u;
    }
    fin[(size_t)bc * N_PAD + o] = u;
  }
  gbar(bslot(a2, 1));

  // ---------------- phase 3: fscan (in-place chunk-prefix over fin) --------
  for (int idx = blockIdx.x * 256 + tid; idx < B_SZ * N_PAD; idx += G * 256) {
    int o = idx % N_PAD;
    int b = idx / N_PAD;
    float* f = fin + (size_t)b * NCHUNK * N_PAD + o;
    float d30 = 1.0f;
#pragma unroll
    for (int i = 0; i < CLEN; ++i) d30 *= DECAY;
    float v[NCHUNK - 1];
#pragma unroll
    for (int c = 0; c < NCHUNK - 1; ++c) v[c] = f[(size_t)c * N_PAD];
    float F = 0.0f;
    f[0] = 0.0f;
#pragma unroll
    for (int c = 1; c < NCHUNK; ++c) {
      F = v[c - 1] + d30 * F;
      f[(size_t)c * N_PAD] = F;
    }
  }
  gbar(bslot(a2, 2));   // also publishes sW2 block-locally

  // ---------------- phase 4: apply_gemm2 -----------------------------------
  {
    const int lane = tid & 63;
    for (int vb = blockIdx.x; vb < AG2_UNITS; vb += G) {
      int m = vb * 4 + (tid >> 6);
      int b = m / T_SZ, t = m % T_SZ;
      int c = t / CLEN, tl = t % CLEN;
      float dp = DECAY;
      for (int i = 0; i < tl; ++i) dp *= DECAY;   // decay^(tl+1), wave-uniform
      const float* frow = fin + (size_t)(b * NCHUNK + c) * N_PAD;
      float p[F_OUT];
#pragma unroll
      for (int o = 0; o < F_OUT; ++o) p[o] = 0.0f;
#pragma unroll
      for (int j = 0; j < 7; ++j) {
        int hh = lane + j * 64;
        float u = a1[(size_t)m * N_PAD + hh];
        if (c > 0) {
          float F = frow[hh];                     // pre-scanned chunk seed
          u = __fadd_rn(u, __fmul_rn(dp, F));
        }
        bool valid = hh < F_HID;
        float s = (u >= THETA && valid) ? 1.0f : 0.0f;
        int hcl = valid ? hh : 0;
#pragma unroll
        for (int o = 0; o < F_OUT; ++o) p[o] = fmaf(s, sW2[o * F_HID + hcl], p[o]);
      }
#pragma unroll
      for (int o = 0; o < F_OUT; ++o)
#pragma unroll
        for (int s = 1; s < 64; s <<= 1) p[o] += __shfl_xor(p[o], s, 64);
      if (lane < F_OUT) a2[(size_t)m * A2_STRIDE + lane] = p[lane];
    }
  }
  gbar(bslot(a2, 3));

  // ---------------- phase 5: psp2 ------------------------------------------
  {
    float (*chf)[F_OUT] = (float (*)[F_OUT])smem;
    float (*seed)[F_OUT] = (float (*)[F_OUT])(smem + sizeof(float) * NCHUNK * F_OUT);
    for (int b = blockIdx.x; b < B_SZ; b += G) {   // <=1 iter per block
      int o = tid / NCHUNK, c = tid % NCHUNK;
      const float* p = a2 + ((size_t)(b * T_SZ + c * CLEN)) * A2_STRIDE + o;
      float v[CLEN];
      float pa[CLEN];
      if (tid < F_OUT * NCHUNK) {
#pragma unroll
        for (int i = 0; i < CLEN; ++i) v[i] = p[(size_t)i * A2_STRIDE];
        float u = 0.0f;
#pragma unroll
        for (int i = 0; i < CLEN; ++i) {
          u = __fadd_rn(__fmul_rn(DECAY, u), v[i]);
          pa[i] = u;
        }
        chf[c][o] = u;
      }
      __syncthreads();
      if (tid < F_OUT) {
        float d30 = 1.0f;
#pragma unroll
        for (int i = 0; i < CLEN; ++i) d30 *= DECAY;
        float F = 0.0f;
        for (int cc = 0; cc < NCHUNK; ++cc) {
          F = chf[cc][tid] + d30 * F;
          seed[cc][tid] = F;
        }
      }
      __syncthreads();
      if (tid < F_OUT * NCHUNK) {
        float F = (c == 0) ? 0.0f : seed[c - 1][o];
        float dp = DECAY;
        float* q = out + (size_t)b * F_OUT * T_SZ + (size_t)o * T_SZ + c * CLEN;
#pragma unroll
        for (int i = 0; i < CLEN; ++i) {
          float u = (c == 0) ? pa[i] : __fadd_rn(pa[i], __fmul_rn(dp, F));
          q[i] = (u >= THETA) ? 1.0f : 0.0f;
          dp *= DECAY;
        }
      }
      __syncthreads();   // protect chf/seed if a block ever looped
    }
  }
}

extern "C" void kernel_launch(void* const* d_in, const int* in_sizes, int n_in,
                              void* d_out, int out_size, void* d_ws, size_t ws_size,
                              hipStream_t stream) {
  const float* inp = (const float*)d_in[0];  // [32,3,32,32]
  const float* W1  = (const float*)d_in[1];  // [410,3072]
  const float* W2  = (const float*)d_in[2];  // [10,410]
  float* out = (float*)d_out;                // [32,10,300]
  char* ws = (char*)d_ws;
  // ws: W1s 1376256 | sbitsT 3686400 | a1 17203200 | fin 573440 | a2 614400
  uint8_t* W1s = (uint8_t*)(ws);
  uint32_t* sbitsT = (uint32_t*)(ws + 1376256);
  float* a1 = (float*)(ws + 1376256 + 3686400);
  float* fin = a1 + (size_t)M_SZ * N_PAD;
  float* a2 = fin + (size_t)B_SZ * NCHUNK * N_PAD;

  // Grid = query-verified resident capacity (required for gbar liveness).
  // LDS 18.4KB => 8 blocks/CU cap; VGPR may lower it — trust the query.
  static int NBLK = 0;
  if (NBLK == 0) {
    int t = 0;
    if (hipOccupancyMaxActiveBlocksPerMultiprocessor(&t, tail, 256, 0) != hipSuccess || t < 1)
      t = 1;
    if (t > 8) t = 8;
    NBLK = t * 256;
  }

  prep<<<dim3(W1_BLOCKS + RNG_BLOCKS), dim3(256), 0, stream>>>(inp, W1, W1s, sbitsT, a2);
  tail<<<dim3(NBLK), dim3(256), 0, stream>>>(sbitsT, W1s, a1, fin, W2, a2, out);
}

// Round 7
// 161.048 us; speedup vs baseline: 3.4724x; 2.0561x over previous
//
#include <hip/hip_runtime.h>
#include <stdint.h>

#define B_SZ 32
#define T_SZ 300
#define F_IN 3072
#define F_HID 410
#define F_OUT 10
#define M_SZ (B_SZ * T_SZ)              // 9600
#define N_PAD 448                       // a1 row stride = gemm1 N (7 x 64)
#define A2_STRIDE 16
#define SB2_STRIDE 16                   // spike-bit words per m (14 used, 16 for align)
#define NCHUNK 10
#define CLEN 30
#define NKB (F_IN / 256)                // 12 K-blocks of 256
#define MT_CNT (M_SZ / 64)              // 150 m-tiles
#define W1_BLOCKS 672                   // 448*3072/8/256
#define RNG_BLOCKS 14400                // 921600*4/256 (4 threads/word, 8 bits each)

// f32(exp(f32(-0.1))) — PSP decay, matches XLA's correctly-rounded exp
#define DECAY 0.90483741803595957f
#define THETA 10.0f
#define KS2 (0x1BD11BDAu ^ 42u)

typedef __attribute__((ext_vector_type(8))) int i32x8;
typedef __attribute__((ext_vector_type(16))) float f32x16;

// FORCED single-instruction rotate-left, in-place. v_alignbit_b32 x,x,x,(32-r)
// = rotl(r). (R3: prep is at the sustainable VALU issue floor.)
#define TF_R(r) { x0 += x1; \
  asm("v_alignbit_b32 %0, %0, %0, %1" : "+v"(x1) : "n"(32 - (r))); \
  x1 ^= x0; }

// JAX partitionable threefry2x32, key=(0,42), ctr=(0, x1i-42). x0 key-add is 0
// (elided); x1 key-add folded into caller's x1i = base + 42 + jj. Returns o0^o1.
__device__ __forceinline__ uint32_t tf_bits(uint32_t x1i) {
  uint32_t x0 = 0u, x1 = x1i;
  TF_R(13) TF_R(15) TF_R(26) TF_R(6)
  x0 += 42u; x1 += KS2 + 1u;
  TF_R(17) TF_R(29) TF_R(16) TF_R(24)
  x0 += KS2; x1 += 2u;
  TF_R(13) TF_R(15) TF_R(26) TF_R(6)
  x1 += 42u + 3u;
  TF_R(17) TF_R(29) TF_R(16) TF_R(24)
  x0 += 42u; x1 += KS2 + 4u;
  TF_R(13) TF_R(15) TF_R(26) TF_R(6)
  x0 += KS2; x1 += 5u;
  return x0 ^ x1;
}

// async global->LDS, 16 B per lane; LDS dest = wave-uniform base + lane*16
__device__ __forceinline__ void gld16(const void* g, void* l) {
  __builtin_amdgcn_global_load_lds(
      (const __attribute__((address_space(1))) uint32_t*)g,
      (__attribute__((address_space(3))) uint32_t*)l, 16, 0, 0);
}

// Merged prep (R4-verified).
// Blocks [0, 672): W1 fp32 -> e4m3, PRE-SWIZZLED into the gemm1 LDS image
//   (rows >= 410 zeroed) so global_load_lds DMA yields conflict-free tiles.
// Blocks [672, 672+14400): partitionable threefry rate-encode, 4 threads per
//   32-bit word. Integer thresholds: u < p <=> (bits>>9) < ceil(p*2^23).
__global__ __launch_bounds__(256) void prep(const float* __restrict__ inp,
                                            const float* __restrict__ W1,
                                            uint8_t* __restrict__ W1s,
                                            uint32_t* __restrict__ sbitsT) {
  if (blockIdx.x < W1_BLOCKS) {
    int idx = blockIdx.x * 256 + threadIdx.x;
    int g = idx * 8;
    int n = g / F_IN;
    int k = g - n * F_IN;
    uint32_t d0 = 0u, d1 = 0u;
    if (n < F_HID) {
      const float* s = W1 + (size_t)n * F_IN + k;
      float4 v0 = ((const float4*)s)[0];
      float4 v1 = ((const float4*)s)[1];
      int t0 = __builtin_amdgcn_cvt_pk_fp8_f32(v0.x, v0.y, 0, false);
      t0 = __builtin_amdgcn_cvt_pk_fp8_f32(v0.z, v0.w, t0, true);
      int t1 = __builtin_amdgcn_cvt_pk_fp8_f32(v1.x, v1.y, 0, false);
      t1 = __builtin_amdgcn_cvt_pk_fp8_f32(v1.z, v1.w, t1, true);
      d0 = (uint32_t)t0; d1 = (uint32_t)t1;
    }
    int nt = n >> 6, r = n & 63;
    int kb = k >> 8, c = (k >> 4) & 15, half = (k >> 3) & 1;
    size_t dst = ((((size_t)nt * NKB + kb) * 64 + r) * 16 + (c ^ (r & 15))) * 16 + half * 8;
    *(uint2*)(W1s + dst) = make_uint2(d0, d1);
  } else {
    uint32_t idx = (blockIdx.x - W1_BLOCKS) * 256u + threadIdx.x;  // [0, 3686400)
    uint32_t q = idx & 3u;          // byte within word
    uint32_t j = idx >> 2;          // word index [0, 921600)
    uint32_t r = j & 63u;
    uint32_t t1 = j >> 6;
    uint32_t wi = t1 & 7u;
    uint32_t t2 = t1 >> 3;          // (mt*12 + kb) in [0, 1800)
    uint32_t kb = t2 % (uint32_t)NKB;
    uint32_t mt = t2 / (uint32_t)NKB;
    uint32_t m = mt * 64u + r;      // GEMM row = b*300 + t
    uint32_t b = m / (uint32_t)T_SZ;
    uint32_t f = (kb * 8u + wi) * 32u + q * 8u;
    const float* p = inp + b * F_IN + f;
    float4 va = ((const float4*)p)[0];
    float4 vb = ((const float4*)p)[1];
    uint32_t T0 = (uint32_t)ceilf(va.x * 8388608.0f);
    uint32_t T1 = (uint32_t)ceilf(va.y * 8388608.0f);
    uint32_t T2 = (uint32_t)ceilf(va.z * 8388608.0f);
    uint32_t T3 = (uint32_t)ceilf(va.w * 8388608.0f);
    uint32_t T4 = (uint32_t)ceilf(vb.x * 8388608.0f);
    uint32_t T5 = (uint32_t)ceilf(vb.y * 8388608.0f);
    uint32_t T6 = (uint32_t)ceilf(vb.z * 8388608.0f);
    uint32_t T7 = (uint32_t)ceilf(vb.w * 8388608.0f);
    uint32_t b42 = m * (uint32_t)F_IN + f + 42u;   // counter base + key lo
    uint32_t w = 0u;
#define GEN(jj, Tn) { uint32_t bits = tf_bits(b42 + (jj)); \
  w |= ((bits >> 9) < (Tn)) ? (1u << (jj)) : 0u; }
    GEN(0, T0) GEN(1, T1) GEN(2, T2) GEN(3, T3)
    GEN(4, T4) GEN(5, T5) GEN(6, T6) GEN(7, T7)
#undef GEN
    ((uint8_t*)sbitsT)[idx] = (uint8_t)w;   // byte q of word j: bits [8q, 8q+8)
  }
}

// a1[m][n] = sum_k spike(m,k)*W1[n][k], MX-fp8 MFMA 32x32x64 (scales=127=2^0).
// BM=64, BN=64, BK=256, grid 150x7=1050, 256 thr = 4 waves (2x2 of 32x32).
// R4-verified 2-phase LDS double-buffer: issue kb+1's DMA, compute kb, one
// barrier per K-block.
__global__ __launch_bounds__(256) void gemm1(const uint32_t* __restrict__ sbitsT,
                                             const uint8_t* __restrict__ W1s,
                                             float* __restrict__ a1) {
  __shared__ uint32_t sAT[2][8 * 64];   // 2x2 KB: [word][row]
  __shared__ uint8_t sB[2][64 * 256];   // 2x16 KB: swizzled LDS image

  const int tid = threadIdx.x;
  const int mtile = blockIdx.x;
  const int nt = blockIdx.y;
  const int m0 = mtile * 64;
  const int n0 = nt * 64;
  const int wv = tid >> 6, lane = tid & 63;
  const int wm = (wv & 1) * 32, wn = (wv >> 1) * 32;
  const int l31 = lane & 31, lh = lane >> 5;

  const uint8_t* gB0 = W1s + (size_t)nt * NKB * 16384;
  const uint8_t* gA0 = (const uint8_t*)sbitsT + (size_t)mtile * NKB * 2048;

  auto STAGE = [&](int buf, int kb) {
    const uint8_t* gB = gB0 + (size_t)kb * 16384;
#pragma unroll
    for (int q = 0; q < 4; ++q)
      gld16(gB + (wv * 4 + q) * 1024 + lane * 16, &sB[buf][(wv * 4 + q) * 1024]);
    if (wv < 2)
      gld16(gA0 + (size_t)kb * 2048 + wv * 1024 + lane * 16,
            (uint8_t*)&sAT[buf][0] + wv * 1024);
  };

  f32x16 acc;
#pragma unroll
  for (int e = 0; e < 16; ++e) acc[e] = 0.0f;

  STAGE(0, 0);
  __syncthreads();             // prologue: only exposed DMA wait
  int cur = 0;
  for (int kb = 0; kb < NKB; ++kb) {
    if (kb + 1 < NKB) STAGE(cur ^ 1, kb + 1);   // in flight during compute
    const uint8_t* sBc = sB[cur];
    const uint32_t* sATc = sAT[cur];
#pragma unroll
    for (int sub = 0; sub < 4; ++sub) {
      // B frag: B[n = wn+l31][k = sub*64 + lh*32 + 0..31]
      int row = wn + l31;
      int cb = sub * 4 + lh * 2;
      uint4 u0 = *(uint4*)&sBc[row * 256 + (((cb + 0) ^ (row & 15)) << 4)];
      uint4 u1 = *(uint4*)&sBc[row * 256 + (((cb + 1) ^ (row & 15)) << 4)];
      i32x8 bfr;
      bfr[0] = u0.x; bfr[1] = u0.y; bfr[2] = u0.z; bfr[3] = u0.w;
      bfr[4] = u1.x; bfr[5] = u1.y; bfr[6] = u1.z; bfr[7] = u1.w;
      // A frag: A[m = wm+l31][same k], expanded bits -> fp8(1.0)=0x38
      uint32_t w = sATc[(sub * 2 + lh) * 64 + wm + l31];
      i32x8 afr;
#pragma unroll
      for (int j = 0; j < 8; ++j) {
        uint32_t n = (w >> (4 * j)) & 15u;
        afr[j] = (int)(((n * 0x204081u) & 0x01010101u) * 0x38u);
      }
      acc = __builtin_amdgcn_mfma_scale_f32_32x32x64_f8f6f4(
          afr, bfr, acc, 0, 0, 0, 127, 0, 127);
    }
    __syncthreads();   // drains this wave's DMA (next buf ready) + LDS reuse
    cur ^= 1;
  }
  // epilogue: C/D 32x32: col = lane&31, row = (reg&3) + 8*(reg>>2) + 4*(lane>>5)
  int col = n0 + wn + l31;
#pragma unroll
  for (int rg = 0; rg < 16; ++rg) {
    int row = m0 + wm + (rg & 3) + 8 * (rg >> 2) + 4 * lh;
    a1[(size_t)row * N_PAD + col] = acc[rg];
  }
}

// R7: psp1 + fscan + threshold merged, NO partial materialization.
// Block = (oblk, b): 640 threads = 10 waves, wave c owns chunk c, lane owns
// column o = oblk*64 + lane. Each thread scans its 30-step chunk in registers
// (same __fadd_rn(__fmul_rn(DECAY,u),x) chain as psp1 => bit-identical),
// chunk finals exchanged via LDS, F~ rebuilt with fscan's exact recurrence,
// u[t] + dp*F~ thresholded, and the 64 spike bits of a wave emitted with ONE
// __ballot per t -> sb2[m][16 words] (2 words/wave, uint2 by lane 0).
// Removes psp1's 17.2 MB partial write + ag2's 17.2 MB re-read + fin buffer.
__global__ __launch_bounds__(640) void scan_spike(const float* __restrict__ a1,
                                                  uint32_t* __restrict__ sb2) {
  __shared__ float fin_s[NCHUNK][64];
  const int oblk = blockIdx.x;          // [0,7)
  const int b = blockIdx.y;             // [0,32)
  const int c = threadIdx.x >> 6;       // chunk = wave id
  const int lane = threadIdx.x & 63;
  const int o = oblk * 64 + lane;
  const float* p = a1 + ((size_t)(b * T_SZ + c * CLEN)) * N_PAD + o;
  float pa[CLEN];
  float u = 0.0f;
#pragma unroll
  for (int i = 0; i < CLEN; ++i) {
    u = __fadd_rn(__fmul_rn(DECAY, u), p[(size_t)i * N_PAD]);
    pa[i] = u;
  }
  fin_s[c][lane] = u;
  __syncthreads();
  float d30 = 1.0f;
#pragma unroll
  for (int i = 0; i < CLEN; ++i) d30 *= DECAY;
  float F = 0.0f;
  for (int cc = 0; cc < c; ++cc)        // fscan's exact chain: F = v + d30*F
    F = fin_s[cc][lane] + d30 * F;
  float dp = DECAY;                     // DECAY^(tl+1), ag2's exact sequence
  const int m0 = b * T_SZ + c * CLEN;
#pragma unroll
  for (int i = 0; i < CLEN; ++i) {
    float uu = (c > 0) ? __fadd_rn(pa[i], __fmul_rn(dp, F)) : pa[i];
    unsigned long long msk = __ballot(uu >= THETA);
    if (lane == 0)
      *(uint2*)&sb2[(size_t)(m0 + i) * SB2_STRIDE + oblk * 2] =
          make_uint2((uint32_t)msk, (uint32_t)(msk >> 32));
    dp *= DECAY;
  }
}

// Layer-2 GEMM from spike BITS. One wave per (b,t); j-loop, fmaf accumulate,
// and shuffle-reduce are byte-identical to the verified ag2 (s is the same
// u>=THETA comparison, precomputed) => bit-exact a2.
__global__ __launch_bounds__(256) void gemm2(const uint32_t* __restrict__ sb2,
                                             const float* __restrict__ W2,
                                             float* __restrict__ a2) {
  __shared__ float sW2[F_OUT * F_HID];   // 16.4 KB
  for (int i = threadIdx.x; i < F_OUT * F_HID; i += 256) sW2[i] = W2[i];
  __syncthreads();
  int m = blockIdx.x * 4 + (threadIdx.x >> 6);
  int lane = threadIdx.x & 63;
  int lh = lane >> 5;
  float p[F_OUT];
#pragma unroll
  for (int o = 0; o < F_OUT; ++o) p[o] = 0.0f;
#pragma unroll
  for (int j = 0; j < 7; ++j) {
    int hh = lane + j * 64;
    uint32_t w = sb2[(size_t)m * SB2_STRIDE + j * 2 + lh];
    float s = (float)((w >> (lane & 31)) & 1u);   // bit==0 for hh>=F_HID by construction
    int hcl = hh < F_HID ? hh : 0;
#pragma unroll
    for (int o = 0; o < F_OUT; ++o) p[o] = fmaf(s, sW2[o * F_HID + hcl], p[o]);
  }
#pragma unroll
  for (int o = 0; o < F_OUT; ++o)
#pragma unroll
    for (int s = 1; s < 64; s <<= 1) p[o] += __shfl_xor(p[o], s, 64);
  if (lane < F_OUT) a2[(size_t)m * A2_STRIDE + lane] = p[lane];
}

// Layer-2 PSP, chunked, one block per batch; lanes (o,c) in [10x10].
__global__ __launch_bounds__(128) void psp2(const float* __restrict__ a2,
                                            float* __restrict__ out) {
  __shared__ float chf[NCHUNK][F_OUT];
  __shared__ float seed[NCHUNK][F_OUT];
  int b = blockIdx.x;
  int tid = threadIdx.x;
  int o = tid / NCHUNK, c = tid % NCHUNK;
  const float* p = a2 + ((size_t)(b * T_SZ + c * CLEN)) * A2_STRIDE + o;
  float v[CLEN];
  float pa[CLEN];
  if (tid < F_OUT * NCHUNK) {
#pragma unroll
    for (int i = 0; i < CLEN; ++i) v[i] = p[(size_t)i * A2_STRIDE];
    float u = 0.0f;
#pragma unroll
    for (int i = 0; i < CLEN; ++i) {
      u = __fadd_rn(__fmul_rn(DECAY, u), v[i]);
      pa[i] = u;
    }
    chf[c][o] = u;
  }
  __syncthreads();
  if (tid < F_OUT) {
    float d30 = 1.0f;
#pragma unroll
    for (int i = 0; i < CLEN; ++i) d30 *= DECAY;
    float F = 0.0f;
    for (int cc = 0; cc < NCHUNK; ++cc) {
      F = chf[cc][tid] + d30 * F;
      seed[cc][tid] = F;
    }
  }
  __syncthreads();
  if (tid < F_OUT * NCHUNK) {
    float F = (c == 0) ? 0.0f : seed[c - 1][o];
    float dp = DECAY;
    float* q = out + (size_t)b * F_OUT * T_SZ + (size_t)o * T_SZ + c * CLEN;
#pragma unroll
    for (int i = 0; i < CLEN; ++i) {
      float u = (c == 0) ? pa[i] : __fadd_rn(pa[i], __fmul_rn(dp, F));
      q[i] = (u >= THETA) ? 1.0f : 0.0f;
      dp *= DECAY;
    }
  }
}

extern "C" void kernel_launch(void* const* d_in, const int* in_sizes, int n_in,
                              void* d_out, int out_size, void* d_ws, size_t ws_size,
                              hipStream_t stream) {
  const float* inp = (const float*)d_in[0];  // [32,3,32,32]
  const float* W1  = (const float*)d_in[1];  // [410,3072]
  const float* W2  = (const float*)d_in[2];  // [10,410]
  float* out = (float*)d_out;                // [32,10,300]
  char* ws = (char*)d_ws;
  // ws: W1s 1376256 | sbitsT 3686400 | a1 17203200 | sb2 614400 | a2 614400
  uint8_t* W1s = (uint8_t*)(ws);
  uint32_t* sbitsT = (uint32_t*)(ws + 1376256);
  float* a1 = (float*)(ws + 1376256 + 3686400);
  uint32_t* sb2 = (uint32_t*)((char*)a1 + (size_t)M_SZ * N_PAD * 4);
  float* a2 = (float*)((char*)sb2 + (size_t)M_SZ * SB2_STRIDE * 4);

  prep<<<dim3(W1_BLOCKS + RNG_BLOCKS), dim3(256), 0, stream>>>(inp, W1, W1s, sbitsT);
  gemm1<<<dim3(MT_CNT, N_PAD / 64), dim3(256), 0, stream>>>(sbitsT, W1s, a1);
  scan_spike<<<dim3(N_PAD / 64, B_SZ), dim3(640), 0, stream>>>(a1, sb2);
  gemm2<<<dim3(M_SZ / 4), dim3(256), 0, stream>>>(sb2, W2, a2);
  psp2<<<dim3(B_SZ), dim3(128), 0, stream>>>(a2, out);
}